// Round 13
// baseline (1517.258 us; speedup 1.0000x reference)
//
#include <hip/hip_runtime.h>
#include <math.h>

#define EMB 50
#define HID 50
#define G4  200   // 4*HID
#define NTAG 5
#define NEGV (-10000.0f)
#define TAG_START 3
#define TAG_STOP  4
#define T_MAX 4096
#define TB 8          // timesteps per k_embed_proj block
#define WPAD 52       // LDS row pad (16B-aligned rows)

typedef float f32x4 __attribute__((ext_vector_type(4)));
typedef float f32x2 __attribute__((ext_vector_type(2)));

#define LO2(v) __builtin_shufflevector(v, v, 0, 1)
#define HI2(v) __builtin_shufflevector(v, v, 2, 3)

// ---------------------------------------------------------------------------
// K1: LDS-staged batched GEMV (r9 structure, unchanged).
// Output pre layout TRANSPOSED + GUARDED:
//   region d: data rows at pre + (d*(T+4) + 2 + t)*200, [unit*4 + gate]
// ---------------------------------------------------------------------------
__global__ __launch_bounds__(256)
void k_embed_proj(const int* __restrict__ sent,
                  const float* __restrict__ embed,
                  const float* __restrict__ Wf, const float* __restrict__ bf,
                  const float* __restrict__ Wb, const float* __restrict__ bb,
                  float* __restrict__ pre, int T) {
  __shared__ __align__(16) float Wl[G4 * WPAD];   // 41.6 KB
  __shared__ __align__(16) float xl[TB * WPAD];   // 1.7 KB
  const int tid = threadIdx.x;
  const int t0  = blockIdx.x * TB;
  int ntt = T - t0; if (ntt > TB) ntt = TB;

  for (int e = tid; e < ntt * EMB; e += 256) {
    int tt = e / EMB, k = e - tt * EMB;
    xl[tt * WPAD + k] = embed[(long long)sent[t0 + tt] * EMB + k];
  }

  for (int ph = 0; ph < 2; ++ph) {
    const float* W = ph ? Wb : Wf;
    const float* b = ph ? bb : bf;
    __syncthreads();
    for (int e = tid; e < G4 * EMB; e += 256) {
      int r = e / EMB, k = e - r * EMB;
      Wl[r * WPAD + k] = W[e];
    }
    __syncthreads();
    float* outBase = pre + ((long long)ph * (T + 4) + 2) * G4;
    for (int o = tid; o < ntt * G4; o += 256) {
      int tt = o / G4, j = o - tt * G4;
      const float* wr_ = &Wl[j * WPAD];
      const float* xx  = &xl[tt * WPAD];
      f32x2 a2 = {0.f, 0.f};
#pragma unroll
      for (int k4 = 0; k4 < 12; ++k4) {
        f32x4 wv = *(const f32x4*)&wr_[4 * k4];
        f32x4 xv = *(const f32x4*)&xx[4 * k4];
        a2 += LO2(wv) * LO2(xv);
        a2 += HI2(wv) * HI2(xv);
      }
      a2.x += wr_[48] * xx[48];
      a2.y += wr_[49] * xx[49];
      float acc = b[j] + a2.x + a2.y;
      int unit = j % HID, gate = j / HID;
      outBase[(long long)(t0 + tt) * G4 + unit * 4 + gate] = acc;
    }
  }
}

// ---------------------------------------------------------------------------
// K2: sequential LSTM — r9/r12 best config, BIT-IDENTICAL (725 cyc/step).
// Quad-split dot, asm-resident weights, guard-row pointer walk, per-lane
// activations, one lgkmcnt(0)+s_barrier per step. Structural floor for this
// decomposition: barrier sync (~100cy) + 16x ds_read_b128 LDS pipe (~190cy,
// 64B/lane = information floor for 16-col split) + dependent chain (~300cy).
// ---------------------------------------------------------------------------
#define DPP_XOR1(v) __int_as_float(__builtin_amdgcn_update_dpp(0, __float_as_int(v), 0xB1, 0xF, 0xF, true))
#define DPP_XOR2(v) __int_as_float(__builtin_amdgcn_update_dpp(0, __float_as_int(v), 0x4E, 0xF, 0xF, true))

__device__ __forceinline__ float dot16(f32x4 w0, f32x4 w1, f32x4 w2, f32x4 w3,
                                       f32x4 x0, f32x4 x1, f32x4 x2, f32x4 x3) {
  f32x2 a = {0.f, 0.f}, b = {0.f, 0.f};
  a += LO2(w0) * LO2(x0);  b += HI2(w0) * HI2(x0);
  a += LO2(w1) * LO2(x1);  b += HI2(w1) * HI2(x1);
  a += LO2(w2) * LO2(x2);  b += HI2(w2) * HI2(x2);
  a += LO2(w3) * LO2(x3);  b += HI2(w3) * HI2(x3);
  return (a.x + b.x) + (a.y + b.y);
}

#define LSTM_STEP(HRbuf, HWbuf)                                              \
  {                                                                          \
    const float* HR = HRbuf;                                                 \
    float*       HW = HWbuf;                                                 \
    f32x4 mp = *(const f32x4*)pp;                                            \
    pp += sG4;                                                               \
    f32x4 x0 = *(const f32x4*)&HR[16 * q + 0];                               \
    f32x4 x1 = *(const f32x4*)&HR[16 * q + 4];                               \
    f32x4 x2 = *(const f32x4*)&HR[16 * q + 8];                               \
    f32x4 x3 = *(const f32x4*)&HR[16 * q + 12];                              \
    float pi = dot16(Wi0, Wi1, Wi2, Wi3, x0, x1, x2, x3);                    \
    float pf = dot16(Wf0, Wf1, Wf2, Wf3, x0, x1, x2, x3);                    \
    float pg = dot16(Wg0, Wg1, Wg2, Wg3, x0, x1, x2, x3);                    \
    float po = dot16(Wo0, Wo1, Wo2, Wo3, x0, x1, x2, x3);                    \
    pi += DPP_XOR1(pi); pi += DPP_XOR2(pi);                                  \
    pf += DPP_XOR1(pf); pf += DPP_XOR2(pf);                                  \
    pg += DPP_XOR1(pg); pg += DPP_XOR2(pg);                                  \
    po += DPP_XOR1(po); po += DPP_XOR2(po);                                  \
    float zi = cp.x + pi, zf = cp.y + pf, zg = cp.z + pg, zo = cp.w + po;    \
    float ei = __expf(-zi), ef2 = __expf(-zf);                               \
    float eg2 = __expf(-zg), eo2 = __expf(-zo);                              \
    float si = __builtin_amdgcn_rcpf(1.f + ei);                              \
    float sf = __builtin_amdgcn_rcpf(1.f + ef2);                             \
    float so = __builtin_amdgcn_rcpf(1.f + eo2);                             \
    float tg = 2.f * __builtin_amdgcn_rcpf(1.f + eg2 * eg2) - 1.f;           \
    c = sf * c + si * tg;                                                    \
    float e2 = __expf(-2.f * c);                                             \
    float tc = 2.f * __builtin_amdgcn_rcpf(1.f + e2) - 1.f;                  \
    float h = so * tc;                                                       \
    if (wr) {                                                                \
      HW[jq] = h;                                                            \
      *hsp = h;                                                              \
    }                                                                        \
    asm volatile("s_waitcnt lgkmcnt(0)\n\ts_barrier" ::: "memory");          \
    hsp += sH;                                                               \
    cp = np; np = mp;                                                        \
  }

__global__ __launch_bounds__(256)
__attribute__((amdgpu_waves_per_eu(1, 1)))
void k_lstm(const float* __restrict__ pre,
            const float* __restrict__ Whh_f,
            const float* __restrict__ Whh_b,
            const float* __restrict__ h0, const float* __restrict__ c0,
            float* __restrict__ hs, int T) {
  const int d   = blockIdx.x;
  const int tid = threadIdx.x;            // 0..255
  const int j   = tid >> 2;               // unit 0..63 (valid < 50)
  const int q   = tid & 3;                // column-slice lane
  const int jq  = (j < HID) ? j : 0;      // clamp for idle quads
  const bool wr = (q == 0) && (j < HID);
  const float* __restrict__ Whh  = d ? Whh_b : Whh_f;
  const float* __restrict__ preD = pre + ((long long)d * (T + 4) + 2) * G4;

  __shared__ __align__(16) float hA[64];
  __shared__ __align__(16) float hB[64];

  const float* p0 = Whh + (long long)(0 * HID + jq) * HID + 16 * q;
  const float* p1 = Whh + (long long)(1 * HID + jq) * HID + 16 * q;
  const float* p2 = Whh + (long long)(2 * HID + jq) * HID + 16 * q;
  const float* p3 = Whh + (long long)(3 * HID + jq) * HID + 16 * q;
  f32x4 Wi0, Wi1, Wi2, Wi3, Wf0, Wf1, Wf2, Wf3;
  f32x4 Wg0, Wg1, Wg2, Wg3, Wo0, Wo1, Wo2, Wo3;
  asm volatile(
      "global_load_dwordx4 %0,  %16, off\n\t"
      "global_load_dwordx4 %1,  %16, off offset:16\n\t"
      "global_load_dwordx4 %2,  %16, off offset:32\n\t"
      "global_load_dwordx4 %3,  %16, off offset:48\n\t"
      "global_load_dwordx4 %4,  %17, off\n\t"
      "global_load_dwordx4 %5,  %17, off offset:16\n\t"
      "global_load_dwordx4 %6,  %17, off offset:32\n\t"
      "global_load_dwordx4 %7,  %17, off offset:48\n\t"
      "global_load_dwordx4 %8,  %18, off\n\t"
      "global_load_dwordx4 %9,  %18, off offset:16\n\t"
      "global_load_dwordx4 %10, %18, off offset:32\n\t"
      "global_load_dwordx4 %11, %18, off offset:48\n\t"
      "global_load_dwordx4 %12, %19, off\n\t"
      "global_load_dwordx4 %13, %19, off offset:16\n\t"
      "global_load_dwordx4 %14, %19, off offset:32\n\t"
      "global_load_dwordx4 %15, %19, off offset:48\n\t"
      "s_waitcnt vmcnt(0)"
      : "=&v"(Wi0), "=&v"(Wi1), "=&v"(Wi2), "=&v"(Wi3),
        "=&v"(Wf0), "=&v"(Wf1), "=&v"(Wf2), "=&v"(Wf3),
        "=&v"(Wg0), "=&v"(Wg1), "=&v"(Wg2), "=&v"(Wg3),
        "=&v"(Wo0), "=&v"(Wo1), "=&v"(Wo2), "=&v"(Wo3)
      : "v"(p0), "v"(p1), "v"(p2), "v"(p3));

  if (q == 3) {   // cols 50..63 are padding: zero those weight elements
    const f32x4 z4 = {0.f, 0.f, 0.f, 0.f};
    Wi0.z = 0.f; Wi0.w = 0.f; Wi1 = z4; Wi2 = z4; Wi3 = z4;
    Wf0.z = 0.f; Wf0.w = 0.f; Wf1 = z4; Wf2 = z4; Wf3 = z4;
    Wg0.z = 0.f; Wg0.w = 0.f; Wg1 = z4; Wg2 = z4; Wg3 = z4;
    Wo0.z = 0.f; Wo0.w = 0.f; Wo1 = z4; Wo2 = z4; Wo3 = z4;
  }

  float c = c0[d * HID + jq];
  if (tid < 64) { hA[tid] = 0.f; hB[tid] = 0.f; }
  __syncthreads();
  if (wr) hA[jq] = h0[d * HID + jq];
  __syncthreads();

  const int s = d ? -1 : 1;
  const int t0 = d ? (T - 1) : 0;
  const long long sG4 = (long long)s * G4;
  const long long sH  = (long long)s * (2 * HID);

  f32x4 cp = *(const f32x4*)&preD[(long long)t0 * G4 + 4 * jq];
  f32x4 np = *(const f32x4*)&preD[(long long)(t0 + s) * G4 + 4 * jq];
  const float* pp = preD + (long long)(t0 + 2 * s) * G4 + 4 * jq;
  float* hsp = hs + (long long)t0 * (2 * HID) + d * HID + jq;

  for (int it = 0; it < T; it += 2) {
    LSTM_STEP(hA, hB)
    LSTM_STEP(hB, hA)
  }
}

// ---------------------------------------------------------------------------
// K3 (round-13): FUSED feats + chunked Viterbi scan + backtrace.
// One 1024-thread block — deletes two kernel launches and their gaps.
//  Phase 1 (all 16 waves): feats[t][m] = bt[m] + Wt[m]·hs[t] (vectorized).
//  Phase 2a (wave 0): per-lane tropical 5x5 chunk operators -> Pl.
//  Phase 2b (wave 0): serial combine over 64 chunk summaries + replay,
//                     writing fvh; lane 63 emits terminal score + last tag.
//  Phase 3 (all): backpointer recompute + suffix-composition backtrace.
// Cross-wave global visibility (feats, fvh, misc) is ordered by
// __syncthreads() per the HIP block memory model.
// ---------------------------------------------------------------------------
__global__ __launch_bounds__(1024)
void k_vfused(const float* __restrict__ hs, const float* __restrict__ Wt,
              const float* __restrict__ bt, const float* __restrict__ trans,
              float* __restrict__ feats, float* __restrict__ fvh,
              float* __restrict__ misc, float* __restrict__ out, int T) {
  __shared__ float Pl[64][26];
  __shared__ unsigned int bufA[T_MAX];
  __shared__ unsigned int bufB[T_MAX];
  const int tid = threadIdx.x;

  // ---- phase 1: feats ----
  for (int g = tid; g < T * NTAG; g += 1024) {
    int t = g / NTAG, m = g - t * NTAG;
    const float* h = hs + (long long)t * (2 * HID);
    const float* w = Wt + m * (2 * HID);
    f32x2 a2 = {0.f, 0.f};
#pragma unroll
    for (int k4 = 0; k4 < 25; ++k4) {
      f32x4 hv = *(const f32x4*)&h[4 * k4];
      f32x4 wv = *(const f32x4*)&w[4 * k4];
      a2 += LO2(wv) * LO2(hv);
      a2 += HI2(wv) * HI2(hv);
    }
    feats[g] = bt[m] + a2.x + a2.y;
  }
  __syncthreads();

  const int L = T >> 6;   // chunk length (T divisible by 64)

  // ---- phase 2a: chunk operators (wave 0) ----
  if (tid < 64) {
    const int c0 = tid * L;
    float tr[NTAG * NTAG];
#pragma unroll
    for (int i = 0; i < NTAG * NTAG; ++i) tr[i] = trans[i];
    float P[25];
    {
      float ft[5];
#pragma unroll
      for (int k = 0; k < 5; ++k) ft[k] = feats[c0 * 5 + k];
#pragma unroll
      for (int n = 0; n < 5; ++n)
#pragma unroll
        for (int p = 0; p < 5; ++p) P[n * 5 + p] = tr[n * 5 + p] + ft[n];
    }
    for (int i = 1; i < L; ++i) {
      int t = c0 + i;
      float ft[5];
#pragma unroll
      for (int k = 0; k < 5; ++k) ft[k] = feats[t * 5 + k];
      float NP[25];
#pragma unroll
      for (int n = 0; n < 5; ++n) {
#pragma unroll
        for (int p = 0; p < 5; ++p) {
          float m = tr[n * 5 + 0] + P[0 + p];
          m = fmaxf(m, tr[n * 5 + 1] + P[5 + p]);
          m = fmaxf(m, tr[n * 5 + 2] + P[10 + p]);
          m = fmaxf(m, tr[n * 5 + 3] + P[15 + p]);
          m = fmaxf(m, tr[n * 5 + 4] + P[20 + p]);
          NP[n * 5 + p] = m + ft[n];
        }
      }
#pragma unroll
      for (int e = 0; e < 25; ++e) P[e] = NP[e];
    }
#pragma unroll
    for (int e = 0; e < 25; ++e) Pl[tid][e] = P[e];
  }
  __syncthreads();

  // ---- phase 2b: serial combine + replay (wave 0) ----
  if (tid < 64) {
    const int c0 = tid * L;
    float tr[NTAG * NTAG];
#pragma unroll
    for (int i = 0; i < NTAG * NTAG; ++i) tr[i] = trans[i];

    float v0 = NEGV, v1 = NEGV, v2 = NEGV, v3 = 0.f, v4 = NEGV;
    float s0 = 0.f, s1 = 0.f, s2 = 0.f, s3 = 0.f, s4 = 0.f;
    for (int cc = 0; cc < 64; ++cc) {
      bool mine = (cc == tid);
      s0 = mine ? v0 : s0; s1 = mine ? v1 : s1; s2 = mine ? v2 : s2;
      s3 = mine ? v3 : s3; s4 = mine ? v4 : s4;
      float nv[5];
#pragma unroll
      for (int n = 0; n < 5; ++n) {
        float m = Pl[cc][n * 5 + 0] + v0;
        m = fmaxf(m, Pl[cc][n * 5 + 1] + v1);
        m = fmaxf(m, Pl[cc][n * 5 + 2] + v2);
        m = fmaxf(m, Pl[cc][n * 5 + 3] + v3);
        m = fmaxf(m, Pl[cc][n * 5 + 4] + v4);
        nv[n] = m;
      }
      v0 = nv[0]; v1 = nv[1]; v2 = nv[2]; v3 = nv[3]; v4 = nv[4];
    }

    float f0 = s0, f1 = s1, f2 = s2, f3 = s3, f4 = s4;
    for (int i = 0; i < L; ++i) {
      int t = c0 + i;
      fvh[t * 5 + 0] = f0; fvh[t * 5 + 1] = f1; fvh[t * 5 + 2] = f2;
      fvh[t * 5 + 3] = f3; fvh[t * 5 + 4] = f4;
      float ft0 = feats[t * 5 + 0], ft1 = feats[t * 5 + 1], ft2 = feats[t * 5 + 2];
      float ft3 = feats[t * 5 + 3], ft4 = feats[t * 5 + 4];
      float n0 = fmaxf(fmaxf(fmaxf(f0 + tr[0],  f1 + tr[1]),  fmaxf(f2 + tr[2],  f3 + tr[3])),  f4 + tr[4])  + ft0;
      float n1 = fmaxf(fmaxf(fmaxf(f0 + tr[5],  f1 + tr[6]),  fmaxf(f2 + tr[7],  f3 + tr[8])),  f4 + tr[9])  + ft1;
      float n2 = fmaxf(fmaxf(fmaxf(f0 + tr[10], f1 + tr[11]), fmaxf(f2 + tr[12], f3 + tr[13])), f4 + tr[14]) + ft2;
      float n3 = fmaxf(fmaxf(fmaxf(f0 + tr[15], f1 + tr[16]), fmaxf(f2 + tr[17], f3 + tr[18])), f4 + tr[19]) + ft3;
      float n4 = fmaxf(fmaxf(fmaxf(f0 + tr[20], f1 + tr[21]), fmaxf(f2 + tr[22], f3 + tr[23])), f4 + tr[24]) + ft4;
      f0 = n0; f1 = n1; f2 = n2; f3 = n3; f4 = n4;
    }

    if (tid == 63) {
      float b0 = f0 + tr[TAG_STOP * 5 + 0], b1 = f1 + tr[TAG_STOP * 5 + 1];
      float b2 = f2 + tr[TAG_STOP * 5 + 2], b3 = f3 + tr[TAG_STOP * 5 + 3];
      float b4 = f4 + tr[TAG_STOP * 5 + 4];
      int last = 0; float best = b0;
      if (b1 > best) { best = b1; last = 1; }
      if (b2 > best) { best = b2; last = 2; }
      if (b3 > best) { best = b3; last = 3; }
      if (b4 > best) { best = b4; last = 4; }
      out[T] = best; misc[0] = (float)last;
    }
  }
  __syncthreads();

  // ---- phase 3: backpointer recompute + suffix-composition backtrace ----
  {
    float tr[NTAG * NTAG];
#pragma unroll
    for (int i = 0; i < NTAG * NTAG; ++i) tr[i] = trans[i];
    for (int t = tid; t < T; t += 1024) {
      unsigned pack;
      if (t == T - 1) {
        pack = 0u | (1u << 3) | (2u << 6) | (3u << 9) | (4u << 12);
      } else {
        const float* fv = fvh + (long long)(t + 1) * 5;
        float g0 = fv[0], g1 = fv[1], g2 = fv[2], g3 = fv[3], g4 = fv[4];
        pack = 0u;
#pragma unroll
        for (int nx = 0; nx < NTAG; ++nx) {
          float v0 = g0 + tr[nx * 5 + 0], v1 = g1 + tr[nx * 5 + 1], v2 = g2 + tr[nx * 5 + 2];
          float v3 = g3 + tr[nx * 5 + 3], v4 = g4 + tr[nx * 5 + 4];
          int bi = 0; float bv = v0;
          if (v1 > bv) { bv = v1; bi = 1; }
          if (v2 > bv) { bv = v2; bi = 2; }
          if (v3 > bv) { bv = v3; bi = 3; }
          if (v4 > bv) { bv = v4; bi = 4; }
          pack |= (unsigned)bi << (3 * nx);
        }
      }
      bufA[t] = pack;
    }
  }
  __syncthreads();

  unsigned int* cur = bufA;
  unsigned int* nxt = bufB;
  for (int dstep = 1; dstep < T; dstep <<= 1) {
    for (int t = tid; t < T; t += 1024) {
      unsigned v = cur[t];
      int u = t + dstep;
      if (u < T) {
        unsigned qq_ = cur[u];
        unsigned r = 0u;
#pragma unroll
        for (int x = 0; x < NTAG; ++x) {
          unsigned qs = (qq_ >> (3 * x)) & 7u;
          unsigned pp = (v >> (3 * qs)) & 7u;
          r |= pp << (3 * x);
        }
        v = r;
      }
      nxt[t] = v;
    }
    __syncthreads();
    unsigned int* tmp = cur; cur = nxt; nxt = tmp;
  }

  int last = (int)misc[0];
  for (int t = tid; t < T; t += 1024) {
    out[t] = (float)((cur[t] >> (3 * last)) & 7u);
  }
}

// ---------------------------------------------------------------------------
extern "C" void kernel_launch(void* const* d_in, const int* in_sizes, int n_in,
                              void* d_out, int out_size, void* d_ws, size_t ws_size,
                              hipStream_t stream) {
  const int*   sent  = (const int*)  d_in[0];
  const float* embed = (const float*)d_in[1];
  const float* Wih_f = (const float*)d_in[2];
  const float* Whh_f = (const float*)d_in[3];
  const float* b_f   = (const float*)d_in[4];
  const float* Wih_b = (const float*)d_in[5];
  const float* Whh_b = (const float*)d_in[6];
  const float* b_b   = (const float*)d_in[7];
  const float* Wt    = (const float*)d_in[8];
  const float* bt    = (const float*)d_in[9];
  const float* trans = (const float*)d_in[10];
  const float* h0    = (const float*)d_in[11];
  const float* c0    = (const float*)d_in[12];
  int T = in_sizes[0];

  float* out = (float*)d_out;
  float* pre   = (float*)d_ws;                       // 2*(T+4)*200 floats (guarded)
  float* hs    = pre + 2 * (size_t)(T + 4) * G4;     // T*100
  float* feats = hs + (size_t)T * 2 * HID;           // T*5
  float* fvh   = feats + (size_t)T * NTAG;           // (T+1)*5
  float* misc  = fvh + (size_t)(T + 1) * NTAG;       // 16

  k_embed_proj<<<(T + TB - 1) / TB, 256, 0, stream>>>(sent, embed, Wih_f, b_f, Wih_b, b_b, pre, T);
  k_lstm<<<2, 256, 0, stream>>>(pre, Whh_f, Whh_b, h0, c0, hs, T);
  k_vfused<<<1, 1024, 0, stream>>>(hs, Wt, bt, trans, feats, fvh, misc, out, T);
}

// Round 14
// 1329.417 us; speedup vs baseline: 1.1413x; 1.1413x over previous
//
#include <hip/hip_runtime.h>
#include <math.h>

#define EMB 50
#define HID 50
#define G4  200   // 4*HID
#define NTAG 5
#define NEGV (-10000.0f)
#define TAG_START 3
#define TAG_STOP  4
#define T_MAX 4096
#define TB 8          // timesteps per k_embed_proj block
#define WPAD 52       // LDS row pad (16B-aligned rows)

typedef float f32x4 __attribute__((ext_vector_type(4)));
typedef float f32x2 __attribute__((ext_vector_type(2)));

#define LO2(v) __builtin_shufflevector(v, v, 0, 1)
#define HI2(v) __builtin_shufflevector(v, v, 2, 3)

// ---------------------------------------------------------------------------
// K1: LDS-staged batched GEMV (r9 structure, unchanged).
// Output pre layout TRANSPOSED + GUARDED:
//   region d: data rows at pre + (d*(T+4) + 2 + t)*200, [unit*4 + gate]
// ---------------------------------------------------------------------------
__global__ __launch_bounds__(256)
void k_embed_proj(const int* __restrict__ sent,
                  const float* __restrict__ embed,
                  const float* __restrict__ Wf, const float* __restrict__ bf,
                  const float* __restrict__ Wb, const float* __restrict__ bb,
                  float* __restrict__ pre, int T) {
  __shared__ __align__(16) float Wl[G4 * WPAD];   // 41.6 KB
  __shared__ __align__(16) float xl[TB * WPAD];   // 1.7 KB
  const int tid = threadIdx.x;
  const int t0  = blockIdx.x * TB;
  int ntt = T - t0; if (ntt > TB) ntt = TB;

  for (int e = tid; e < ntt * EMB; e += 256) {
    int tt = e / EMB, k = e - tt * EMB;
    xl[tt * WPAD + k] = embed[(long long)sent[t0 + tt] * EMB + k];
  }

  for (int ph = 0; ph < 2; ++ph) {
    const float* W = ph ? Wb : Wf;
    const float* b = ph ? bb : bf;
    __syncthreads();
    for (int e = tid; e < G4 * EMB; e += 256) {
      int r = e / EMB, k = e - r * EMB;
      Wl[r * WPAD + k] = W[e];
    }
    __syncthreads();
    float* outBase = pre + ((long long)ph * (T + 4) + 2) * G4;
    for (int o = tid; o < ntt * G4; o += 256) {
      int tt = o / G4, j = o - tt * G4;
      const float* wr_ = &Wl[j * WPAD];
      const float* xx  = &xl[tt * WPAD];
      f32x2 a2 = {0.f, 0.f};
#pragma unroll
      for (int k4 = 0; k4 < 12; ++k4) {
        f32x4 wv = *(const f32x4*)&wr_[4 * k4];
        f32x4 xv = *(const f32x4*)&xx[4 * k4];
        a2 += LO2(wv) * LO2(xv);
        a2 += HI2(wv) * HI2(xv);
      }
      a2.x += wr_[48] * xx[48];
      a2.y += wr_[49] * xx[49];
      float acc = b[j] + a2.x + a2.y;
      int unit = j % HID, gate = j / HID;
      outBase[(long long)(t0 + tt) * G4 + unit * 4 + gate] = acc;
    }
  }
}

// ---------------------------------------------------------------------------
// K2: sequential LSTM — r9/r12 best config, BIT-IDENTICAL (725 cyc/step).
// Quad-split dot, asm-resident weights, guard-row pointer walk, per-lane
// activations, one lgkmcnt(0)+s_barrier per step.
// ---------------------------------------------------------------------------
#define DPP_XOR1(v) __int_as_float(__builtin_amdgcn_update_dpp(0, __float_as_int(v), 0xB1, 0xF, 0xF, true))
#define DPP_XOR2(v) __int_as_float(__builtin_amdgcn_update_dpp(0, __float_as_int(v), 0x4E, 0xF, 0xF, true))

__device__ __forceinline__ float dot16(f32x4 w0, f32x4 w1, f32x4 w2, f32x4 w3,
                                       f32x4 x0, f32x4 x1, f32x4 x2, f32x4 x3) {
  f32x2 a = {0.f, 0.f}, b = {0.f, 0.f};
  a += LO2(w0) * LO2(x0);  b += HI2(w0) * HI2(x0);
  a += LO2(w1) * LO2(x1);  b += HI2(w1) * HI2(x1);
  a += LO2(w2) * LO2(x2);  b += HI2(w2) * HI2(x2);
  a += LO2(w3) * LO2(x3);  b += HI2(w3) * HI2(x3);
  return (a.x + b.x) + (a.y + b.y);
}

#define LSTM_STEP(HRbuf, HWbuf)                                              \
  {                                                                          \
    const float* HR = HRbuf;                                                 \
    float*       HW = HWbuf;                                                 \
    f32x4 mp = *(const f32x4*)pp;                                            \
    pp += sG4;                                                               \
    f32x4 x0 = *(const f32x4*)&HR[16 * q + 0];                               \
    f32x4 x1 = *(const f32x4*)&HR[16 * q + 4];                               \
    f32x4 x2 = *(const f32x4*)&HR[16 * q + 8];                               \
    f32x4 x3 = *(const f32x4*)&HR[16 * q + 12];                              \
    float pi = dot16(Wi0, Wi1, Wi2, Wi3, x0, x1, x2, x3);                    \
    float pf = dot16(Wf0, Wf1, Wf2, Wf3, x0, x1, x2, x3);                    \
    float pg = dot16(Wg0, Wg1, Wg2, Wg3, x0, x1, x2, x3);                    \
    float po = dot16(Wo0, Wo1, Wo2, Wo3, x0, x1, x2, x3);                    \
    pi += DPP_XOR1(pi); pi += DPP_XOR2(pi);                                  \
    pf += DPP_XOR1(pf); pf += DPP_XOR2(pf);                                  \
    pg += DPP_XOR1(pg); pg += DPP_XOR2(pg);                                  \
    po += DPP_XOR1(po); po += DPP_XOR2(po);                                  \
    float zi = cp.x + pi, zf = cp.y + pf, zg = cp.z + pg, zo = cp.w + po;    \
    float ei = __expf(-zi), ef2 = __expf(-zf);                               \
    float eg2 = __expf(-zg), eo2 = __expf(-zo);                              \
    float si = __builtin_amdgcn_rcpf(1.f + ei);                              \
    float sf = __builtin_amdgcn_rcpf(1.f + ef2);                             \
    float so = __builtin_amdgcn_rcpf(1.f + eo2);                             \
    float tg = 2.f * __builtin_amdgcn_rcpf(1.f + eg2 * eg2) - 1.f;           \
    c = sf * c + si * tg;                                                    \
    float e2 = __expf(-2.f * c);                                             \
    float tc = 2.f * __builtin_amdgcn_rcpf(1.f + e2) - 1.f;                  \
    float h = so * tc;                                                       \
    if (wr) {                                                                \
      HW[jq] = h;                                                            \
      *hsp = h;                                                              \
    }                                                                        \
    asm volatile("s_waitcnt lgkmcnt(0)\n\ts_barrier" ::: "memory");          \
    hsp += sH;                                                               \
    cp = np; np = mp;                                                        \
  }

__global__ __launch_bounds__(256)
__attribute__((amdgpu_waves_per_eu(1, 1)))
void k_lstm(const float* __restrict__ pre,
            const float* __restrict__ Whh_f,
            const float* __restrict__ Whh_b,
            const float* __restrict__ h0, const float* __restrict__ c0,
            float* __restrict__ hs, int T) {
  const int d   = blockIdx.x;
  const int tid = threadIdx.x;            // 0..255
  const int j   = tid >> 2;               // unit 0..63 (valid < 50)
  const int q   = tid & 3;                // column-slice lane
  const int jq  = (j < HID) ? j : 0;      // clamp for idle quads
  const bool wr = (q == 0) && (j < HID);
  const float* __restrict__ Whh  = d ? Whh_b : Whh_f;
  const float* __restrict__ preD = pre + ((long long)d * (T + 4) + 2) * G4;

  __shared__ __align__(16) float hA[64];
  __shared__ __align__(16) float hB[64];

  const float* p0 = Whh + (long long)(0 * HID + jq) * HID + 16 * q;
  const float* p1 = Whh + (long long)(1 * HID + jq) * HID + 16 * q;
  const float* p2 = Whh + (long long)(2 * HID + jq) * HID + 16 * q;
  const float* p3 = Whh + (long long)(3 * HID + jq) * HID + 16 * q;
  f32x4 Wi0, Wi1, Wi2, Wi3, Wf0, Wf1, Wf2, Wf3;
  f32x4 Wg0, Wg1, Wg2, Wg3, Wo0, Wo1, Wo2, Wo3;
  asm volatile(
      "global_load_dwordx4 %0,  %16, off\n\t"
      "global_load_dwordx4 %1,  %16, off offset:16\n\t"
      "global_load_dwordx4 %2,  %16, off offset:32\n\t"
      "global_load_dwordx4 %3,  %16, off offset:48\n\t"
      "global_load_dwordx4 %4,  %17, off\n\t"
      "global_load_dwordx4 %5,  %17, off offset:16\n\t"
      "global_load_dwordx4 %6,  %17, off offset:32\n\t"
      "global_load_dwordx4 %7,  %17, off offset:48\n\t"
      "global_load_dwordx4 %8,  %18, off\n\t"
      "global_load_dwordx4 %9,  %18, off offset:16\n\t"
      "global_load_dwordx4 %10, %18, off offset:32\n\t"
      "global_load_dwordx4 %11, %18, off offset:48\n\t"
      "global_load_dwordx4 %12, %19, off\n\t"
      "global_load_dwordx4 %13, %19, off offset:16\n\t"
      "global_load_dwordx4 %14, %19, off offset:32\n\t"
      "global_load_dwordx4 %15, %19, off offset:48\n\t"
      "s_waitcnt vmcnt(0)"
      : "=&v"(Wi0), "=&v"(Wi1), "=&v"(Wi2), "=&v"(Wi3),
        "=&v"(Wf0), "=&v"(Wf1), "=&v"(Wf2), "=&v"(Wf3),
        "=&v"(Wg0), "=&v"(Wg1), "=&v"(Wg2), "=&v"(Wg3),
        "=&v"(Wo0), "=&v"(Wo1), "=&v"(Wo2), "=&v"(Wo3)
      : "v"(p0), "v"(p1), "v"(p2), "v"(p3));

  if (q == 3) {   // cols 50..63 are padding: zero those weight elements
    const f32x4 z4 = {0.f, 0.f, 0.f, 0.f};
    Wi0.z = 0.f; Wi0.w = 0.f; Wi1 = z4; Wi2 = z4; Wi3 = z4;
    Wf0.z = 0.f; Wf0.w = 0.f; Wf1 = z4; Wf2 = z4; Wf3 = z4;
    Wg0.z = 0.f; Wg0.w = 0.f; Wg1 = z4; Wg2 = z4; Wg3 = z4;
    Wo0.z = 0.f; Wo0.w = 0.f; Wo1 = z4; Wo2 = z4; Wo3 = z4;
  }

  float c = c0[d * HID + jq];
  if (tid < 64) { hA[tid] = 0.f; hB[tid] = 0.f; }
  __syncthreads();
  if (wr) hA[jq] = h0[d * HID + jq];
  __syncthreads();

  const int s = d ? -1 : 1;
  const int t0 = d ? (T - 1) : 0;
  const long long sG4 = (long long)s * G4;
  const long long sH  = (long long)s * (2 * HID);

  f32x4 cp = *(const f32x4*)&preD[(long long)t0 * G4 + 4 * jq];
  f32x4 np = *(const f32x4*)&preD[(long long)(t0 + s) * G4 + 4 * jq];
  const float* pp = preD + (long long)(t0 + 2 * s) * G4 + 4 * jq;
  float* hsp = hs + (long long)t0 * (2 * HID) + d * HID + jq;

  for (int it = 0; it < T; it += 2) {
    LSTM_STEP(hA, hB)
    LSTM_STEP(hB, hA)
  }
}

// ---------------------------------------------------------------------------
// K3: feats[t][m] = bt[m] + Wt[m]·hs[t]   (dot over 100)
// ---------------------------------------------------------------------------
__global__ void k_feats(const float* __restrict__ hs, const float* __restrict__ Wt,
                        const float* __restrict__ bt, float* __restrict__ feats, int T) {
  int g = blockIdx.x * blockDim.x + threadIdx.x;
  if (g >= T * NTAG) return;
  int t = g / NTAG, m = g % NTAG;
  const float* h = hs + (long long)t * (2 * HID);
  const float* w = Wt + m * (2 * HID);
  float a = bt[m];
#pragma unroll
  for (int k = 0; k < 2 * HID; ++k) a += w[k] * h[k];
  feats[g] = a;
}

// ---------------------------------------------------------------------------
// K4a: PARALLEL chunked Viterbi scan (r10 structure, unchanged).
// Kept as its OWN kernel with __launch_bounds__(64,1): the serial tropical
// fold needs ~80 live VGPRs/lane — fusing it into a 1024-thread kernel
// (r13) capped the register budget and spilled it (+190us). Register-heavy
// serial phases must not share a kernel with wide parallel phases.
// ---------------------------------------------------------------------------
__global__ __launch_bounds__(64, 1)
void k_vchunk(const float* __restrict__ feats,
              const float* __restrict__ trans,
              float* __restrict__ fvh, float* __restrict__ misc,
              float* __restrict__ out, int T) {
  const int lane = threadIdx.x;
  const int L    = T >> 6;
  const int c0   = lane * L;

  __shared__ float Pl[64][26];

  float tr[NTAG * NTAG];
#pragma unroll
  for (int i = 0; i < NTAG * NTAG; ++i) tr[i] = trans[i];

  float P[25];
  {
    float ft[5];
#pragma unroll
    for (int k = 0; k < 5; ++k) ft[k] = feats[c0 * 5 + k];
#pragma unroll
    for (int n = 0; n < 5; ++n)
#pragma unroll
      for (int p = 0; p < 5; ++p) P[n * 5 + p] = tr[n * 5 + p] + ft[n];
  }
  for (int i = 1; i < L; ++i) {
    int t = c0 + i;
    float ft[5];
#pragma unroll
    for (int k = 0; k < 5; ++k) ft[k] = feats[t * 5 + k];
    float NP[25];
#pragma unroll
    for (int n = 0; n < 5; ++n) {
#pragma unroll
      for (int p = 0; p < 5; ++p) {
        float m = tr[n * 5 + 0] + P[0 + p];
        m = fmaxf(m, tr[n * 5 + 1] + P[5 + p]);
        m = fmaxf(m, tr[n * 5 + 2] + P[10 + p]);
        m = fmaxf(m, tr[n * 5 + 3] + P[15 + p]);
        m = fmaxf(m, tr[n * 5 + 4] + P[20 + p]);
        NP[n * 5 + p] = m + ft[n];
      }
    }
#pragma unroll
    for (int e = 0; e < 25; ++e) P[e] = NP[e];
  }
#pragma unroll
  for (int e = 0; e < 25; ++e) Pl[lane][e] = P[e];
  __syncthreads();

  float v0 = NEGV, v1 = NEGV, v2 = NEGV, v3 = 0.f, v4 = NEGV;
  float s0 = 0.f, s1 = 0.f, s2 = 0.f, s3 = 0.f, s4 = 0.f;
  for (int cc = 0; cc < 64; ++cc) {
    bool mine = (cc == lane);
    s0 = mine ? v0 : s0; s1 = mine ? v1 : s1; s2 = mine ? v2 : s2;
    s3 = mine ? v3 : s3; s4 = mine ? v4 : s4;
    float nv[5];
#pragma unroll
    for (int n = 0; n < 5; ++n) {
      float m = Pl[cc][n * 5 + 0] + v0;
      m = fmaxf(m, Pl[cc][n * 5 + 1] + v1);
      m = fmaxf(m, Pl[cc][n * 5 + 2] + v2);
      m = fmaxf(m, Pl[cc][n * 5 + 3] + v3);
      m = fmaxf(m, Pl[cc][n * 5 + 4] + v4);
      nv[n] = m;
    }
    v0 = nv[0]; v1 = nv[1]; v2 = nv[2]; v3 = nv[3]; v4 = nv[4];
  }

  float f0 = s0, f1 = s1, f2 = s2, f3 = s3, f4 = s4;
  for (int i = 0; i < L; ++i) {
    int t = c0 + i;
    fvh[t * 5 + 0] = f0; fvh[t * 5 + 1] = f1; fvh[t * 5 + 2] = f2;
    fvh[t * 5 + 3] = f3; fvh[t * 5 + 4] = f4;
    float ft0 = feats[t * 5 + 0], ft1 = feats[t * 5 + 1], ft2 = feats[t * 5 + 2];
    float ft3 = feats[t * 5 + 3], ft4 = feats[t * 5 + 4];
    float n0 = fmaxf(fmaxf(fmaxf(f0 + tr[0],  f1 + tr[1]),  fmaxf(f2 + tr[2],  f3 + tr[3])),  f4 + tr[4])  + ft0;
    float n1 = fmaxf(fmaxf(fmaxf(f0 + tr[5],  f1 + tr[6]),  fmaxf(f2 + tr[7],  f3 + tr[8])),  f4 + tr[9])  + ft1;
    float n2 = fmaxf(fmaxf(fmaxf(f0 + tr[10], f1 + tr[11]), fmaxf(f2 + tr[12], f3 + tr[13])), f4 + tr[14]) + ft2;
    float n3 = fmaxf(fmaxf(fmaxf(f0 + tr[15], f1 + tr[16]), fmaxf(f2 + tr[17], f3 + tr[18])), f4 + tr[19]) + ft3;
    float n4 = fmaxf(fmaxf(fmaxf(f0 + tr[20], f1 + tr[21]), fmaxf(f2 + tr[22], f3 + tr[23])), f4 + tr[24]) + ft4;
    f0 = n0; f1 = n1; f2 = n2; f3 = n3; f4 = n4;
  }

  if (lane == 63) {
    float b0 = f0 + tr[TAG_STOP * 5 + 0], b1 = f1 + tr[TAG_STOP * 5 + 1];
    float b2 = f2 + tr[TAG_STOP * 5 + 2], b3 = f3 + tr[TAG_STOP * 5 + 3];
    float b4 = f4 + tr[TAG_STOP * 5 + 4];
    int last = 0; float best = b0;
    if (b1 > best) { best = b1; last = 1; }
    if (b2 > best) { best = b2; last = 2; }
    if (b3 > best) { best = b3; last = 3; }
    if (b4 > best) { best = b4; last = 4; }
    out[T] = best; misc[0] = (float)last;
  }
}

// ---------------------------------------------------------------------------
// K4b: parallel backpointer recompute + suffix-composition backtrace.
// ---------------------------------------------------------------------------
__global__ __launch_bounds__(1024) void k_vbt(const float* __restrict__ trans,
                        const float* __restrict__ fvh, const float* __restrict__ misc,
                        float* __restrict__ out, int T) {
  __shared__ unsigned int bufA[T_MAX];
  __shared__ unsigned int bufB[T_MAX];
  int tid = threadIdx.x;

  {
    float tr[NTAG * NTAG];
#pragma unroll
    for (int i = 0; i < NTAG * NTAG; ++i) tr[i] = trans[i];
    for (int t = tid; t < T; t += 1024) {
      unsigned pack;
      if (t == T - 1) {
        pack = 0u | (1u << 3) | (2u << 6) | (3u << 9) | (4u << 12);
      } else {
        const float* fv = fvh + (long long)(t + 1) * 5;
        float g0 = fv[0], g1 = fv[1], g2 = fv[2], g3 = fv[3], g4 = fv[4];
        pack = 0u;
#pragma unroll
        for (int nx = 0; nx < NTAG; ++nx) {
          float v0 = g0 + tr[nx * 5 + 0], v1 = g1 + tr[nx * 5 + 1], v2 = g2 + tr[nx * 5 + 2];
          float v3 = g3 + tr[nx * 5 + 3], v4 = g4 + tr[nx * 5 + 4];
          int bi = 0; float bv = v0;
          if (v1 > bv) { bv = v1; bi = 1; }
          if (v2 > bv) { bv = v2; bi = 2; }
          if (v3 > bv) { bv = v3; bi = 3; }
          if (v4 > bv) { bv = v4; bi = 4; }
          pack |= (unsigned)bi << (3 * nx);
        }
      }
      bufA[t] = pack;
    }
  }
  __syncthreads();

  unsigned int* cur = bufA;
  unsigned int* nxt = bufB;
  for (int dstep = 1; dstep < T; dstep <<= 1) {
    for (int t = tid; t < T; t += 1024) {
      unsigned v = cur[t];
      int u = t + dstep;
      if (u < T) {
        unsigned qq_ = cur[u];
        unsigned r = 0u;
#pragma unroll
        for (int x = 0; x < NTAG; ++x) {
          unsigned qs = (qq_ >> (3 * x)) & 7u;
          unsigned pp = (v >> (3 * qs)) & 7u;
          r |= pp << (3 * x);
        }
        v = r;
      }
      nxt[t] = v;
    }
    __syncthreads();
    unsigned int* tmp = cur; cur = nxt; nxt = tmp;
  }

  int last = (int)misc[0];
  for (int t = tid; t < T; t += 1024) {
    out[t] = (float)((cur[t] >> (3 * last)) & 7u);
  }
}

// ---------------------------------------------------------------------------
extern "C" void kernel_launch(void* const* d_in, const int* in_sizes, int n_in,
                              void* d_out, int out_size, void* d_ws, size_t ws_size,
                              hipStream_t stream) {
  const int*   sent  = (const int*)  d_in[0];
  const float* embed = (const float*)d_in[1];
  const float* Wih_f = (const float*)d_in[2];
  const float* Whh_f = (const float*)d_in[3];
  const float* b_f   = (const float*)d_in[4];
  const float* Wih_b = (const float*)d_in[5];
  const float* Whh_b = (const float*)d_in[6];
  const float* b_b   = (const float*)d_in[7];
  const float* Wt    = (const float*)d_in[8];
  const float* bt    = (const float*)d_in[9];
  const float* trans = (const float*)d_in[10];
  const float* h0    = (const float*)d_in[11];
  const float* c0    = (const float*)d_in[12];
  int T = in_sizes[0];

  float* out = (float*)d_out;
  float* pre   = (float*)d_ws;                       // 2*(T+4)*200 floats (guarded)
  float* hs    = pre + 2 * (size_t)(T + 4) * G4;     // T*100
  float* feats = hs + (size_t)T * 2 * HID;           // T*5
  float* fvh   = feats + (size_t)T * NTAG;           // (T+1)*5
  float* misc  = fvh + (size_t)(T + 1) * NTAG;       // 16

  k_embed_proj<<<(T + TB - 1) / TB, 256, 0, stream>>>(sent, embed, Wih_f, b_f, Wih_b, b_b, pre, T);
  k_lstm<<<2, 256, 0, stream>>>(pre, Whh_f, Whh_b, h0, c0, hs, T);
  k_feats<<<(T * NTAG + 255) / 256, 256, 0, stream>>>(hs, Wt, bt, feats, T);
  k_vchunk<<<1, 64, 0, stream>>>(feats, trans, fvh, misc, out, T);
  k_vbt<<<1, 1024, 0, stream>>>(trans, fvh, misc, out, T);
}